// Round 9
// baseline (689.969 us; speedup 1.0000x reference)
//
#include <hip/hip_runtime.h>
#include <math.h>

#define MFMA __builtin_amdgcn_mfma_f32_16x16x32_bf16
typedef __attribute__((ext_vector_type(8))) short bf16x8;
typedef __attribute__((ext_vector_type(4))) float f32x4;
typedef unsigned short ushort_t;

__device__ __forceinline__ unsigned short tbf_hi(float x) {
    return (unsigned short)(__float_as_uint(x) >> 16);
}
__device__ __forceinline__ unsigned short tbf_lo(float x) {
    unsigned u = __float_as_uint(x);
    float r = x - __uint_as_float(u & 0xFFFF0000u);
    return (unsigned short)(__float_as_uint(r) >> 16);
}
__device__ __forceinline__ unsigned packhi(unsigned u0, unsigned u1) {
#if __has_builtin(__builtin_amdgcn_perm)
    return __builtin_amdgcn_perm(u1, u0, 0x07060302u);
#else
    return (u1 & 0xFFFF0000u) | (u0 >> 16);
#endif
}
__device__ __forceinline__ void tsplit8(const float* v, unsigned* hw, unsigned* lw) {
#pragma unroll
    for (int t = 0; t < 4; ++t) {
        unsigned u0 = __float_as_uint(v[2 * t]);
        unsigned u1 = __float_as_uint(v[2 * t + 1]);
        float r0 = v[2 * t]     - __uint_as_float(u0 & 0xFFFF0000u);
        float r1 = v[2 * t + 1] - __uint_as_float(u1 & 0xFFFF0000u);
        hw[t] = packhi(u0, u1);
        lw[t] = packhi(__float_as_uint(r0), __float_as_uint(r1));
    }
}

#if __has_builtin(__builtin_amdgcn_global_load_lds)
#define HAVE_GLDS 1
__device__ __forceinline__ void gld16(const ushort_t* g, ushort_t* l) {
    __builtin_amdgcn_global_load_lds(
        (const __attribute__((address_space(1))) unsigned int*)g,
        (__attribute__((address_space(3))) unsigned int*)l, 16, 0, 0);
}
#else
#define HAVE_GLDS 0
#endif

// ---------------- LN stats (for fp32 intermediates) ----------------
__global__ __launch_bounds__(256) void ln_stats_kernel(
    const float* __restrict__ src, float* __restrict__ mu,
    float* __restrict__ rs, int rows) {
    int row = blockIdx.x * 4 + (threadIdx.x >> 6);
    int lane = threadIdx.x & 63;
    if (row >= rows) return;
    const float* p = src + (size_t)row * 384;
    float s = 0.f, sq = 0.f;
#pragma unroll
    for (int i = 0; i < 6; ++i) {
        float v = p[lane + 64 * i];
        s += v; sq += v * v;
    }
#pragma unroll
    for (int off = 32; off > 0; off >>= 1) {
        s += __shfl_down(s, off);
        sq += __shfl_down(sq, off);
    }
    if (lane == 0) {
        float m = s / 384.f;
        float var = sq / 384.f - m * m;
        mu[row] = m;
        rs[row] = rsqrtf(var + 1e-6f);
    }
}

// ---------------- fused LN stats + raw hi/lo split (for raw inputs) ----------------
__global__ __launch_bounds__(256) void lnsplit_kernel(
    const float* __restrict__ src, float* __restrict__ mu,
    float* __restrict__ rs, ushort_t* __restrict__ dh,
    ushort_t* __restrict__ dl, int rows) {
    int row = blockIdx.x * 4 + (threadIdx.x >> 6);
    int lane = threadIdx.x & 63;
    if (row >= rows) return;
    const float* p = src + (size_t)row * 384;
    float v[6];
    float s = 0.f, sq = 0.f;
#pragma unroll
    for (int i = 0; i < 6; ++i) {
        v[i] = p[lane + 64 * i];
        s += v[i]; sq += v[i] * v[i];
    }
#pragma unroll
    for (int i = 0; i < 6; ++i) {
        dh[(size_t)row * 384 + lane + 64 * i] = tbf_hi(v[i]);
        dl[(size_t)row * 384 + lane + 64 * i] = tbf_lo(v[i]);
    }
#pragma unroll
    for (int off = 32; off > 0; off >>= 1) {
        s += __shfl_down(s, off);
        sq += __shfl_down(sq, off);
    }
    if (lane == 0) {
        float m = s / 384.f;
        float var = sq / 384.f - m * m;
        mu[row] = m;
        rs[row] = rsqrtf(var + 1e-6f);
    }
}

// ---------------- weight prep ----------------
struct WprepTab {
    const float* src[10]; const float* g[10];
    ushort_t* dh[10]; ushort_t* dl[10];
    float scale[10]; int N[10];
};
__global__ __launch_bounds__(256) void wprep_all(WprepTab t) {
    int e = blockIdx.y;
    int N = t.N[e];
    int idx = blockIdx.x * 256 + threadIdx.x;
    if (idx >= N * 384) return;
    int n = idx / 384, k = idx % 384;
    float x = t.src[e][(size_t)k * N + n] * t.scale[e];
    if (t.g[e]) x *= t.g[e][k];
    t.dh[e][idx] = tbf_hi(x);
    t.dl[e][idx] = tbf_lo(x);
}

// ---------------- cm/cb vectors (LN fold) + b67 ----------------
struct CmcbTab {
    const float* src[5]; const float* g[5]; const float* lb[5]; const float* badd[5];
    float* cm[5]; float* cb[5]; float scale[5]; int N[5];
};
__global__ __launch_bounds__(256) void cmcb_all(CmcbTab t) {
    int e = blockIdx.y;
    int N = t.N[e];
    int c = blockIdx.x * 4 + (threadIdx.x >> 6);
    int lane = threadIdx.x & 63;
    if (c >= N) return;
    float s1 = 0.f, s2 = 0.f;
    const float* gp = t.g[e];
#pragma unroll
    for (int i = 0; i < 6; ++i) {
        int k = lane + 64 * i;
        float w = t.src[e][(size_t)k * N + c];
        if (gp) s1 += gp[k] * w;
        s2 += t.lb[e][k] * w;
    }
#pragma unroll
    for (int off = 32; off > 0; off >>= 1) {
        s1 += __shfl_down(s1, off);
        s2 += __shfl_down(s2, off);
    }
    if (lane == 0) {
        if (t.cm[e]) t.cm[e][c] = -t.scale[e] * s1;
        float v = t.scale[e] * s2;
        if (t.badd[e]) v += t.badd[e][c];
        t.cb[e][c] = v;
    }
}

// ---------------- split-bf16 MFMA GEMM, 384-col slot outputs ----------------
struct Slot {
    const float* bias; const float* cm; const float* cb;
    float* f32o; ushort_t* oh; ushort_t* ol;
    int mode; int kvsh;
};
struct GemmCfg { const float* muA; const float* rsA; Slot s[4]; };

template <int TM, int TN, int ASPLIT, int XSWZ>
__global__ __launch_bounds__(256) void gemm_k(
    const float* __restrict__ Af,
    const ushort_t* __restrict__ Ah, const ushort_t* __restrict__ Al,
    const ushort_t* __restrict__ Bh, const ushort_t* __restrict__ Bl,
    GemmCfg cfg) {
    constexpr int MI = TM / 64;
    constexpr int NI = TN / 16;
    constexpr int AR = TM / 32, BR = TN / 32;
#if HAVE_GLDS
    constexpr int PIPE = ASPLIT;
#else
    constexpr int PIPE = 0;
#endif
    constexpr int NBUF = PIPE ? 2 : 1;
    __shared__ __align__(16) ushort_t Alds[NBUF][2][TM * 64];
    __shared__ __align__(16) ushort_t Blds[NBUF][2][TN * 64];
    int bx = blockIdx.x, by = blockIdx.y;
    if (XSWZ) {
        int gx = gridDim.x;
        int nwg = gx * gridDim.y;
        int lin = by * gx + bx;
        int cpx = nwg >> 3;
        lin = (lin & 7) * cpx + (lin >> 3);
        by = lin / gx;
        bx = lin - by * gx;
    }
    int m0 = by * TM, n0 = bx * TN;
    int tid = threadIdx.x;
    int w = tid >> 6, lane = tid & 63;
    int j = lane & 15, kg = lane >> 4;
    int srow = tid >> 3, sk16 = tid & 7;
    f32x4 acc[MI][NI];
#pragma unroll
    for (int mi = 0; mi < MI; ++mi)
#pragma unroll
        for (int ni = 0; ni < NI; ++ni)
#pragma unroll
            for (int r = 0; r < 4; ++r) acc[mi][ni][r] = 0.f;

#if HAVE_GLDS
    auto stage = [&](int ks, int buf) {
#pragma unroll
        for (int i = 0; i < AR; ++i) {
            int lrow = w * (TM / 4) + i * 8 + (lane >> 3);
            int cc = (lane & 7) ^ (lrow & 7);
            size_t ga = (size_t)(m0 + lrow) * 384 + ks * 64 + cc * 8;
            gld16(Ah + ga, &Alds[buf][0][(w * (TM / 4) + i * 8) * 64]);
            gld16(Al + ga, &Alds[buf][1][(w * (TM / 4) + i * 8) * 64]);
        }
#pragma unroll
        for (int i = 0; i < BR; ++i) {
            int lrow = w * (TN / 4) + i * 8 + (lane >> 3);
            int cc = (lane & 7) ^ (lrow & 7);
            size_t gb = (size_t)(n0 + lrow) * 384 + ks * 64 + cc * 8;
            gld16(Bh + gb, &Blds[buf][0][(w * (TN / 4) + i * 8) * 64]);
            gld16(Bl + gb, &Blds[buf][1][(w * (TN / 4) + i * 8) * 64]);
        }
    };
#endif

    auto compute = [&](int buf) {
#pragma unroll
        for (int kf = 0; kf < 2; ++kf) {
            bf16x8 afh[MI], afl[MI], bfh[NI], bfl[NI];
#pragma unroll
            for (int mi = 0; mi < MI; ++mi) {
                int row = w * (TM / 4) + mi * 16 + j;
                int off = (row << 6) + ((((kf << 2) | kg) ^ (row & 7)) << 3);
                afh[mi] = *(const bf16x8*)&Alds[buf][0][off];
                afl[mi] = *(const bf16x8*)&Alds[buf][1][off];
            }
#pragma unroll
            for (int ni = 0; ni < NI; ++ni) {
                int col = ni * 16 + j;
                int off = (col << 6) + ((((kf << 2) | kg) ^ (col & 7)) << 3);
                bfh[ni] = *(const bf16x8*)&Blds[buf][0][off];
                bfl[ni] = *(const bf16x8*)&Blds[buf][1][off];
            }
#pragma unroll
            for (int mi = 0; mi < MI; ++mi)
#pragma unroll
                for (int ni = 0; ni < NI; ++ni) {
                    acc[mi][ni] = MFMA(afh[mi], bfh[ni], acc[mi][ni], 0, 0, 0);
                    acc[mi][ni] = MFMA(afh[mi], bfl[ni], acc[mi][ni], 0, 0, 0);
                    acc[mi][ni] = MFMA(afl[mi], bfh[ni], acc[mi][ni], 0, 0, 0);
                }
        }
    };

#if HAVE_GLDS
    if (PIPE) {
        // 2-phase double-buffered pipeline, counted vmcnt (T3+T4 minimum form)
        stage(0, 0);
        int cur = 0;
        for (int ks = 0; ks < 6; ++ks) {
            if (ks < 5) {
                stage(ks + 1, cur ^ 1);
                // 12 loads in flight for next tile (TM=128) / 8 (TM=64);
                // wait only for current tile's batch.
                if constexpr (2 * (AR + BR) == 12)
                    asm volatile("s_waitcnt vmcnt(12)" ::: "memory");
                else
                    asm volatile("s_waitcnt vmcnt(8)" ::: "memory");
            } else {
                asm volatile("s_waitcnt vmcnt(0)" ::: "memory");
            }
            __builtin_amdgcn_s_barrier();
            __builtin_amdgcn_sched_barrier(0);
            compute(cur);
            __builtin_amdgcn_sched_barrier(0);
            asm volatile("s_waitcnt lgkmcnt(0)" ::: "memory");
            __builtin_amdgcn_sched_barrier(0);
            __builtin_amdgcn_s_barrier();
            cur ^= 1;
        }
    } else
#endif
    {
        for (int ks = 0; ks < 6; ++ks) {
            int kbase = ks * 64 + sk16 * 8;
            __syncthreads();
#pragma unroll
            for (int rnd = 0; rnd < AR; ++rnd) {
                int row = srow + rnd * 32;
                int off = (row << 6) + ((sk16 ^ (row & 7)) << 3);
                if (ASPLIT) {
                    size_t ga = (size_t)(m0 + row) * 384 + kbase;
                    *(bf16x8*)&Alds[0][0][off] = *(const bf16x8*)(Ah + ga);
                    *(bf16x8*)&Alds[0][1][off] = *(const bf16x8*)(Al + ga);
                } else {
                    const float* ap = Af + (size_t)(m0 + row) * 384 + kbase;
                    float v[8];
                    *(float4*)v = *(const float4*)ap;
                    *(float4*)(v + 4) = *(const float4*)(ap + 4);
                    unsigned hw[4], lw[4];
                    tsplit8(v, hw, lw);
                    *(uint4*)&Alds[0][0][off] = *(uint4*)hw;
                    *(uint4*)&Alds[0][1][off] = *(uint4*)lw;
                }
            }
#pragma unroll
            for (int rnd = 0; rnd < BR; ++rnd) {
                int row = srow + rnd * 32;
                int off = (row << 6) + ((sk16 ^ (row & 7)) << 3);
                size_t gb = (size_t)(n0 + row) * 384 + kbase;
                *(bf16x8*)&Blds[0][0][off] = *(const bf16x8*)(Bh + gb);
                *(bf16x8*)&Blds[0][1][off] = *(const bf16x8*)(Bl + gb);
            }
            __syncthreads();
            compute(0);
        }
    }

    int slot = n0 / 384;
    Slot sl = cfg.s[slot];
    int cb0 = n0 % 384;
#pragma unroll
    for (int mi = 0; mi < MI; ++mi)
#pragma unroll
        for (int ni = 0; ni < NI; ++ni)
#pragma unroll
            for (int r = 0; r < 4; ++r) {
                int row = m0 + w * (TM / 4) + mi * 16 + kg * 4 + r;
                int c2 = cb0 + ni * 16 + j;
                float v = acc[mi][ni][r];
                if (sl.cm) {
                    float rss = cfg.rsA[row];
                    v = rss * v + rss * cfg.muA[row] * sl.cm[c2] + sl.cb[c2];
                }
                if (sl.bias) v += sl.bias[c2];
                if (sl.mode == 0) {
                    sl.f32o[(size_t)row * 384 + c2] = v;
                } else if (sl.mode == 1) {
                    sl.f32o[(size_t)row * 384 + c2] = tanhf(v);
                } else if (sl.mode == 2) {
                    sl.oh[(size_t)row * 384 + c2] = tbf_hi(v);
                    sl.ol[(size_t)row * 384 + c2] = tbf_lo(v);
                } else if (sl.mode == 4) {
                    size_t o = (size_t)c2 * 384 + row;
                    sl.oh[o] = tbf_hi(v);
                    sl.ol[o] = tbf_lo(v);
                } else {
                    int bb = row >> sl.kvsh;
                    int key = row & ((1 << sl.kvsh) - 1);
                    size_t o = (((size_t)bb * 384 + c2) << sl.kvsh) + key;
                    sl.oh[o] = tbf_hi(v);
                    sl.ol[o] = tbf_lo(v);
                }
            }
}

// ---------------- MFMA flash attention, key-chunked, split-bf16 ----------------
template <int HD, int DPAD, int NW, int GAUSS, int FINAL>
__global__ __launch_bounds__(64 * NW) void attn_k(
    const ushort_t* __restrict__ Qh, const ushort_t* __restrict__ Ql,
    const ushort_t* __restrict__ Kh, const ushort_t* __restrict__ Kl,
    const ushort_t* __restrict__ Vth, const ushort_t* __restrict__ Vtl,
    const float* __restrict__ PT,
    ushort_t* __restrict__ Xh, ushort_t* __restrict__ Xl,
    float* __restrict__ Opart, float* __restrict__ ML,
    int kvsh, int nch, int NS, int nh) {
    constexpr int KS = DPAD / 32;
    constexpr int NSUB = HD / 16;
    constexpr int C8 = DPAD / 8;
    constexpr int NT = 64 * NW;
    __shared__ __align__(16) ushort_t Ksh[2][32][DPAD + 8];
    __shared__ __align__(16) ushort_t Vsh[2][HD][40];
    __shared__ __align__(16) ushort_t Psh[NW][2][16][40];
    __shared__ float ptbl[GAUSS ? 64 : 1];
    int b = blockIdx.z, h = blockIdx.y, chunk = blockIdx.x;
    int tid = threadIdx.x;
    int w = tid >> 6, lane = tid & 63;
    int l15 = lane & 15, kg = lane >> 4;

    bf16x8 qf[2][KS];
    {
        size_t qa = (size_t)(b * 64 + w * 16 + l15) * 384 + h * HD + kg * 8;
#pragma unroll
        for (int ks = 0; ks < KS; ++ks) {
            if (ks * 32 + kg * 8 < HD) {
                qf[0][ks] = *(const bf16x8*)(Qh + qa + ks * 32);
                qf[1][ks] = *(const bf16x8*)(Ql + qa + ks * 32);
            } else {
                qf[0][ks] = bf16x8{};
                qf[1][ks] = bf16x8{};
            }
        }
    }
    if (GAUSS) {
        if (tid < 64) ptbl[tid] = PT[b * 64 + tid];
    }
    f32x4 oacc[NSUB];
#pragma unroll
    for (int ns = 0; ns < NSUB; ++ns)
#pragma unroll
        for (int r = 0; r < 4; ++r) oacc[ns][r] = 0.f;
    float m_run[4], l_run[4];
#pragma unroll
    for (int r = 0; r < 4; ++r) { m_run[r] = -1e30f; l_run[r] = 0.f; }

    int kbase0 = chunk * nch;
    for (int t = 0; t < nch; t += 32) {
        int n0 = kbase0 + t;
        __syncthreads();
        for (int i = tid; i < 2 * 32 * C8; i += NT) {
            int hl = i / (32 * C8);
            int rem = i - hl * 32 * C8;
            int key = rem / C8, c = rem % C8;
            bf16x8 v;
            if (c * 8 < HD) {
                const ushort_t* src = (hl ? Kl : Kh) +
                    ((size_t)((b << kvsh) + n0 + key)) * 384 + h * HD + c * 8;
                v = *(const bf16x8*)src;
            } else {
                v = bf16x8{};
            }
            *(bf16x8*)&Ksh[hl][key][c * 8] = v;
        }
        for (int i = tid; i < 2 * HD * 4; i += NT) {
            int hl = i / (HD * 4);
            int rem = i - hl * HD * 4;
            int dim = rem >> 2, c = rem & 3;
            const ushort_t* src = (hl ? Vtl : Vth) +
                (((size_t)(b * 384 + h * HD + dim)) << kvsh) + n0 + c * 8;
            *(bf16x8*)&Vsh[hl][dim][c * 8] = *(const bf16x8*)src;
        }
        __syncthreads();

        f32x4 shh[2], slh[2], shl[2];
#pragma unroll
        for (int sub = 0; sub < 2; ++sub)
#pragma unroll
            for (int r = 0; r < 4; ++r) { shh[sub][r] = 0.f; slh[sub][r] = 0.f; shl[sub][r] = 0.f; }
#pragma unroll
        for (int sub = 0; sub < 2; ++sub)
#pragma unroll
            for (int ks = 0; ks < KS; ++ks) {
                bf16x8 kh8 = *(const bf16x8*)&Ksh[0][sub * 16 + l15][ks * 32 + kg * 8];
                bf16x8 kl8 = *(const bf16x8*)&Ksh[1][sub * 16 + l15][ks * 32 + kg * 8];
                shh[sub] = MFMA(qf[0][ks], kh8, shh[sub], 0, 0, 0);
                slh[sub] = MFMA(qf[1][ks], kh8, slh[sub], 0, 0, 0);
                shl[sub] = MFMA(qf[0][ks], kl8, shl[sub], 0, 0, 0);
            }
        f32x4 s[2];
#pragma unroll
        for (int sub = 0; sub < 2; ++sub)
#pragma unroll
            for (int r = 0; r < 4; ++r)
                s[sub][r] = shh[sub][r] + slh[sub][r] + shl[sub][r];
        if (GAUSS) {
            int win = n0 >> 7;
#pragma unroll
            for (int sub = 0; sub < 2; ++sub) {
                float wpos = (float)((n0 + sub * 16 + l15) & 127);
#pragma unroll
                for (int r = 0; r < 4; ++r) {
                    float ptv = ptbl[((w * 16 + kg * 4 + r) * 8 + win) & 63];
                    float d = wpos - ptv;
                    s[sub][r] *= __expf(d * d * (-1.0f / 18.0f));
                }
            }
        }
#pragma unroll
        for (int r = 0; r < 4; ++r) {
            float v = fmaxf(s[0][r], s[1][r]);
            v = fmaxf(v, __shfl_xor(v, 1));
            v = fmaxf(v, __shfl_xor(v, 2));
            v = fmaxf(v, __shfl_xor(v, 4));
            v = fmaxf(v, __shfl_xor(v, 8));
            float mnew = fmaxf(m_run[r], v);
            float alpha = __expf(m_run[r] - mnew);
            m_run[r] = mnew;
            float p0 = __expf(s[0][r] - mnew);
            float p1 = __expf(s[1][r] - mnew);
            float ps = p0 + p1;
            ps += __shfl_xor(ps, 1);
            ps += __shfl_xor(ps, 2);
            ps += __shfl_xor(ps, 4);
            ps += __shfl_xor(ps, 8);
            l_run[r] = l_run[r] * alpha + ps;
#pragma unroll
            for (int ns = 0; ns < NSUB; ++ns) oacc[ns][r] *= alpha;
            Psh[w][0][kg * 4 + r][l15] = tbf_hi(p0);
            Psh[w][1][kg * 4 + r][l15] = tbf_lo(p0);
            Psh[w][0][kg * 4 + r][16 + l15] = tbf_hi(p1);
            Psh[w][1][kg * 4 + r][16 + l15] = tbf_lo(p1);
        }
        bf16x8 pfh = *(const bf16x8*)&Psh[w][0][l15][kg * 8];
        bf16x8 pfl = *(const bf16x8*)&Psh[w][1][l15][kg * 8];
#pragma unroll
        for (int ns = 0; ns < NSUB; ++ns) {
            bf16x8 vh8 = *(const bf16x8*)&Vsh[0][ns * 16 + l15][kg * 8];
            bf16x8 vl8 = *(const bf16x8*)&Vsh[1][ns * 16 + l15][kg * 8];
            oacc[ns] = MFMA(pfh, vh8, oacc[ns], 0, 0, 0);
            oacc[ns] = MFMA(pfl, vh8, oacc[ns], 0, 0, 0);
            oacc[ns] = MFMA(pfh, vl8, oacc[ns], 0, 0, 0);
        }
    }
    if (FINAL) {
#pragma unroll
        for (int ns = 0; ns < NSUB; ++ns)
#pragma unroll
            for (int r = 0; r < 4; ++r) {
                float val = oacc[ns][r] / l_run[r];
                size_t o = (size_t)(b * 64 + w * 16 + kg * 4 + r) * 384 +
                           h * HD + ns * 16 + l15;
                Xh[o] = tbf_hi(val);
                Xl[o] = tbf_lo(val);
            }
    } else {
#pragma unroll
        for (int r = 0; r < 4; ++r) {
            int rq = w * 16 + kg * 4 + r;
            size_t Pidx = ((size_t)((b * nh + h) * 64 + rq)) * NS + chunk;
#pragma unroll
            for (int ns = 0; ns < NSUB; ++ns)
                Opart[Pidx * HD + ns * 16 + l15] = oacc[ns][r];
            if (l15 == 0) {
                ML[Pidx * 2] = m_run[r];
                ML[Pidx * 2 + 1] = l_run[r];
            }
        }
    }
}

// ---------------- flash combine ----------------
template <int HD>
__global__ __launch_bounds__(256) void comb_k(
    const float* __restrict__ Opart, const float* __restrict__ ML,
    ushort_t* __restrict__ Xh, ushort_t* __restrict__ Xl,
    int NS, int nh) {
    int gw = blockIdx.x * 4 + (threadIdx.x >> 6);
    int lane = threadIdx.x & 63;
    if (gw >= 2048 * nh) return;
    int r_ = gw / nh, h = gw % nh;
    int b = r_ >> 6, rq = r_ & 63;
    size_t Pb = ((size_t)((b * nh + h) * 64 + rq)) * NS;
    float M = -1e30f;
    for (int c = 0; c < NS; ++c) M = fmaxf(M, ML[(Pb + c) * 2]);
    float wgt[8];
    float L = 0.f;
    for (int c = 0; c < NS; ++c) {
        wgt[c] = __expf(ML[(Pb + c) * 2] - M);
        L += wgt[c] * ML[(Pb + c) * 2 + 1];
    }
    float invL = 1.f / L;
    for (int d = lane; d < HD; d += 64) {
        float o = 0.f;
        for (int c = 0; c < NS; ++c) o += wgt[c] * Opart[(Pb + c) * HD + d];
        o *= invL;
        size_t xo = (size_t)r_ * 384 + h * HD + d;
        Xh[xo] = tbf_hi(o);
        Xl[xo] = tbf_lo(o);
    }
}

// ---------------- p_t head ----------------
__global__ __launch_bounds__(256) void pt_kernel(
    const float* __restrict__ T, const float* __restrict__ vpw,
    const float* __restrict__ vpb, float* __restrict__ pt, int rows) {
    int row = blockIdx.x * 4 + (threadIdx.x >> 6);
    int lane = threadIdx.x & 63;
    if (row >= rows) return;
    const float* p = T + (size_t)row * 384;
    float s = 0.f;
#pragma unroll
    for (int i = 0; i < 6; ++i) s += p[lane + 64 * i] * vpw[lane + 64 * i];
#pragma unroll
    for (int off = 32; off > 0; off >>= 1) s += __shfl_down(s, off);
    if (lane == 0) {
        float x = s + vpb[0];
        pt[row] = 128.f / (1.f + __expf(-x));
    }
}

extern "C" void kernel_launch(void* const* d_in, const int* in_sizes, int n_in,
                              void* d_out, int out_size, void* d_ws, size_t ws_size,
                              hipStream_t stream) {
    const float* q       = (const float*)d_in[0];
    const float* kv      = (const float*)d_in[1];
    const float* Wq      = (const float*)d_in[2];
    const float* Wkv     = (const float*)d_in[3];
    const float* Wproj   = (const float*)d_in[4];
    const float* bproj   = (const float*)d_in[5];
    const float* Wp_w    = (const float*)d_in[6];
    const float* Wp_b    = (const float*)d_in[7];
    const float* vp_w    = (const float*)d_in[8];
    const float* vp_b    = (const float*)d_in[9];
    const float* qpos_w  = (const float*)d_in[10];
    const float* qpos_b  = (const float*)d_in[11];
    const float* ca1_Wq  = (const float*)d_in[12];
    const float* ca1_Wkv = (const float*)d_in[13];
    const float* ca1_Wp  = (const float*)d_in[14];
    const float* ca1_bp  = (const float*)d_in[15];
    const float* ca2_Wq  = (const float*)d_in[16];
    const float* ca2_Wkv = (const float*)d_in[17];
    const float* ca2_Wp  = (const float*)d_in[18];
    const float* ca2_bp  = (const float*)d_in[19];
    const float* lnq1_g  = (const float*)d_in[20];
    const float* lnq1_b  = (const float*)d_in[21];
    const float* lnkv1_g = (const float*)d_in[22];
    const float* lnkv1_b = (const float*)d_in[23];
    const float* lnq2_g  = (const float*)d_in[24];
    const float* lnq2_b  = (const float*)d_in[25];
    const float* lnkv2_g = (const float*)d_in[26];
    const float* lnkv2_b = (const float*)d_in[27];
    float* out = (float*)d_out;

    const float SC_CA = 0.07216878364870323f;   // 192^-0.5
    const float SC_MA = 0.14433756729740643f;   // 48^-0.5

    float* F = (float*)d_ws;
    float* R0 = F;    F += 786432;
    float* R1 = F;    F += 786432;
    float* MUq = F;   F += 2048;
    float* RSq = F;   F += 2048;
    float* MUkv = F;  F += 32768;
    float* RSkv = F;  F += 32768;
    float* MUpa = F;  F += 2048;
    float* RSpa = F;  F += 2048;
    float* MUpb = F;  F += 2048;
    float* RSpb = F;  F += 2048;
    float* PTb = F;   F += 2048;
    float* CM = F;    F += 2304;
    float* CB = F;    F += 2688;
    float* OP = F;    F += 6291456;
    float* MLb = F;   F += 262144;
    ushort_t* U = (ushort_t*)F;
    ushort_t* WB1h = U; U += 589824;
    ushort_t* WB1l = U; U += 589824;
    ushort_t* WB5h = U; U += 589824;   // [ca2_K | ca2_V | main_K | main_V] weights, 1536x384
    ushort_t* WB5l = U; U += 589824;
    ushort_t* W2h = U;  U += 147456;
    ushort_t* W2l = U;  U += 147456;
    ushort_t* W3h = U;  U += 147456;
    ushort_t* W3l = U;  U += 147456;
    ushort_t* W4h = U;  U += 147456;
    ushort_t* W4l = U;  U += 147456;
    ushort_t* W67h = U; U += 147456;
    ushort_t* W67l = U; U += 147456;
    ushort_t* W7h = U;  U += 147456;
    ushort_t* W7l = U;  U += 147456;
    ushort_t* W10h = U; U += 147456;
    ushort_t* W10l = U; U += 147456;
    ushort_t* Qch = U;  U += 786432;
    ushort_t* Qcl = U;  U += 786432;
    ushort_t* Qmh = U;  U += 786432;
    ushort_t* Qml = U;  U += 786432;
    ushort_t* Xh = U;   U += 786432;
    ushort_t* Xl = U;   U += 786432;
    ushort_t* K1h = U;  U += 786432;
    ushort_t* K1l = U;  U += 786432;
    ushort_t* V1h = U;  U += 786432;
    ushort_t* V1l = U;  U += 786432;
    ushort_t* K2h = U;  U += 12582912;
    ushort_t* K2l = U;  U += 12582912;
    ushort_t* V2h = U;  U += 12582912;
    ushort_t* V2l = U;  U += 12582912;
    ushort_t* Qsh = U;  U += 786432;
    ushort_t* Qsl = U;  U += 786432;
    ushort_t* KVsh = U; U += 12582912;
    ushort_t* KVsl = U; U += 12582912;
    // ALIAS: main-attn K/V reuse the CA2 K/V region (dead after CA2 attention).
    ushort_t* Kmh = K2h;
    ushort_t* Kml = K2l;
    ushort_t* Vmh = V2h;
    ushort_t* Vml = V2l;

    dim3 blk(256);

    // fused stats + raw split on inputs
    lnsplit_kernel<<<512, blk, 0, stream>>>(q, MUq, RSq, Qsh, Qsl, 2048);
    lnsplit_kernel<<<8192, blk, 0, stream>>>(kv, MUkv, RSkv, KVsh, KVsl, 32768);

    // weight prep
    WprepTab wt{};
    const float* wsrc[10] = {qpos_w, ca1_Wkv, Wq, ca2_Wkv, Wkv,
                             ca1_Wq, ca1_Wp, ca2_Wq, Wp_w, Wproj};
    const float* wg[10] = {nullptr, lnkv1_g, nullptr, lnkv2_g, nullptr,
                           lnq1_g, nullptr, lnq2_g, nullptr, nullptr};
    ushort_t* wdh[10] = {WB1h, WB1h + 384 * 384, WB1h + 1152 * 384,
                         WB5h, WB5h + 768 * 384, W2h, W3h, W4h, W7h, W10h};
    ushort_t* wdl[10] = {WB1l, WB1l + 384 * 384, WB1l + 1152 * 384,
                         WB5l, WB5l + 768 * 384, W2l, W3l, W4l, W7l, W10l};
    float wsc[10] = {1.f, 1.f, SC_MA, 1.f, 1.f, SC_CA, 1.f, SC_CA, 1.f, 1.f};
    int wn[10] = {384, 768, 384, 768, 768, 384, 384, 384, 384, 384};
    for (int i = 0; i < 10; ++i) {
        wt.src[i] = wsrc[i]; wt.g[i] = wg[i]; wt.dh[i] = wdh[i];
        wt.dl[i] = wdl[i]; wt.scale[i] = wsc[i]; wt.N[i] = wn[i];
    }
    wprep_all<<<dim3(1152, 10), blk, 0, stream>>>(wt);

    // cm/cb (LN folds) + b67
    CmcbTab ct{};
    const float* csrc[5] = {ca1_Wq, ca1_Wkv, ca2_Wq, ca2_Wkv, Wp_w};
    const float* cg[5] = {lnq1_g, lnkv1_g, lnq2_g, lnkv2_g, nullptr};
    const float* cl[5] = {lnq1_b, lnkv1_b, lnq2_b, lnkv2_b, ca2_bp};
    const float* cbad[5] = {nullptr, nullptr, nullptr, nullptr, Wp_b};
    float* ccm[5] = {CM, CM + 384, CM + 1152, CM + 1536, nullptr};
    float* ccb[5] = {CB, CB + 384, CB + 1152, CB + 1536, CB + 2304};
    float csc[5] = {SC_CA, 1.f, SC_CA, 1.f, 1.f};
    int cn[5] = {384, 768, 384, 768, 384};
    for (int i = 0; i < 5; ++i) {
        ct.src[i] = csrc[i]; ct.g[i] = cg[i]; ct.lb[i] = cl[i]; ct.badd[i] = cbad[i];
        ct.cm[i] = ccm[i]; ct.cb[i] = ccb[i]; ct.scale[i] = csc[i]; ct.N[i] = cn[i];
    }
    cmcb_all<<<dim3(192, 5), blk, 0, stream>>>(ct);

    // W67 = ca2_Wp @ Wp_w  (transposed-split output for B-use)
    GemmCfg gW{};
    gW.s[0] = {nullptr, nullptr, nullptr, nullptr, W67h, W67l, 4, 0};
    gemm_k<64, 64, 0, 0><<<dim3(6, 6), blk, 0, stream>>>(ca2_Wp, nullptr, nullptr, W7h, W7l, gW);

    // G5a: A=kv split [32768], W = [ca2_K | ca2_V], 128x64, XCD swizzle, pipelined
    GemmCfg g5a{};
    g5a.muA = MUkv; g5a.rsA = RSkv;
    g5a.s[0] = {nullptr, CM + 1536, CB + 1536, nullptr, K2h, K2l, 2, 0};
    g5a.s[1] = {nullptr, CM + 1920, CB + 1920, nullptr, V2h, V2l, 3, 10};
    gemm_k<128, 64, 1, 1><<<dim3(12, 256), blk, 0, stream>>>(nullptr, KVsh, KVsl, WB5h, WB5l, g5a);

    // G1: A=q split [2048], W = [qpos | ca1_K (LN q) | ca1_V (LN q) | mainQ]
    GemmCfg g1{};
    g1.muA = MUq; g1.rsA = RSq;
    g1.s[0] = {qpos_b, nullptr, nullptr, R0, nullptr, nullptr, 0, 0};
    g1.s[1] = {nullptr, CM + 384, CB + 384, nullptr, K1h, K1l, 2, 0};
    g1.s[2] = {nullptr, CM + 768, CB + 768, nullptr, V1h, V1l, 3, 6};
    g1.s[3] = {nullptr, nullptr, nullptr, nullptr, Qmh, Qml, 2, 0};
    gemm_k<64, 64, 1, 1><<<dim3(24, 32), blk, 0, stream>>>(nullptr, Qsh, Qsl, WB1h, WB1l, g1);

    ln_stats_kernel<<<512, blk, 0, stream>>>(R0, MUpa, RSpa, 2048);

    // G2: CAQ1 = LN(P_A) @ ca1_Wq * sc
    GemmCfg g2{};
    g2.muA = MUpa; g2.rsA = RSpa;
    g2.s[0] = {nullptr, CM, CB, nullptr, Qch, Qcl, 2, 0};
    gemm_k<64, 64, 0, 0><<<dim3(6, 32), blk, 0, stream>>>(R0, nullptr, nullptr, W2h, W2l, g2);

    // CA1 attention (64 keys, final)
    attn_k<192, 192, 4, 0, 1><<<dim3(1, 2, 32), blk, 0, stream>>>(
        Qch, Qcl, K1h, K1l, V1h, V1l, nullptr, Xh, Xl, nullptr, nullptr, 6, 64, 1, 2);

    // G3: P_B = X @ ca1_Wp + bp
    GemmCfg g3{};
    g3.s[0] = {ca1_bp, nullptr, nullptr, R1, nullptr, nullptr, 0, 0};
    gemm_k<64, 64, 1, 0><<<dim3(6, 32), blk, 0, stream>>>(nullptr, Xh, Xl, W3h, W3l, g3);

    ln_stats_kernel<<<512, blk, 0, stream>>>(R1, MUpb, RSpb, 2048);

    // G4: CAQ2 = LN(P_B) @ ca2_Wq * sc
    GemmCfg g4{};
    g4.muA = MUpb; g4.rsA = RSpb;
    g4.s[0] = {nullptr, CM + 1152, CB + 1152, nullptr, Qch, Qcl, 2, 0};
    gemm_k<64, 64, 0, 0><<<dim3(6, 32), blk, 0, stream>>>(R1, nullptr, nullptr, W4h, W4l, g4);

    // CA2 attention (1024 keys, 8 chunks) + combine
    attn_k<192, 192, 4, 0, 0><<<dim3(8, 2, 32), blk, 0, stream>>>(
        Qch, Qcl, K2h, K2l, V2h, V2l, nullptr, nullptr, nullptr, OP, MLb, 10, 128, 8, 2);
    comb_k<192><<<1024, blk, 0, stream>>>(OP, MLb, Xh, Xl, 8, 2);

    // G67: T = tanh(X @ W67 + b67)
    GemmCfg g67{};
    g67.s[0] = {CB + 2304, nullptr, nullptr, R0, nullptr, nullptr, 1, 0};
    gemm_k<64, 64, 1, 0><<<dim3(6, 32), blk, 0, stream>>>(nullptr, Xh, Xl, W67h, W67l, g67);

    pt_kernel<<<512, blk, 0, stream>>>(R0, vp_w, vp_b, PTb, 2048);

    // G5b: main K/V projection (aliased onto K2/V2 region; CA2 done reading it)
    GemmCfg g5b{};
    g5b.s[0] = {nullptr, nullptr, nullptr, nullptr, Kmh, Kml, 2, 0};
    g5b.s[1] = {nullptr, nullptr, nullptr, nullptr, Vmh, Vml, 3, 10};
    gemm_k<128, 64, 1, 1><<<dim3(12, 256), blk, 0, stream>>>(nullptr, KVsh, KVsl,
        WB5h + 768 * 384, WB5l + 768 * 384, g5b);

    // main attention (gauss, 8 chunks) + combine
    attn_k<48, 64, 4, 1, 0><<<dim3(8, 8, 32), blk, 0, stream>>>(
        Qmh, Qml, Kmh, Kml, Vmh, Vml, PTb, nullptr, nullptr, OP, MLb, 10, 128, 8, 8);
    comb_k<48><<<4096, blk, 0, stream>>>(OP, MLb, Xh, Xl, 8, 8);

    // G10: out = X @ Wproj + bproj
    GemmCfg g10{};
    g10.s[0] = {bproj, nullptr, nullptr, out, nullptr, nullptr, 0, 0};
    gemm_k<64, 64, 1, 0><<<dim3(6, 32), blk, 0, stream>>>(nullptr, Xh, Xl, W10h, W10l, g10);
}

// Round 10
// 451.478 us; speedup vs baseline: 1.5282x; 1.5282x over previous
//
#include <hip/hip_runtime.h>
#include <math.h>

#define MFMA __builtin_amdgcn_mfma_f32_16x16x32_bf16
typedef __attribute__((ext_vector_type(8))) short bf16x8;
typedef __attribute__((ext_vector_type(4))) float f32x4;
typedef __attribute__((ext_vector_type(4))) unsigned short us4;
typedef unsigned short ushort_t;

__device__ __forceinline__ unsigned short tbf_hi(float x) {
    return (unsigned short)(__float_as_uint(x) >> 16);
}
__device__ __forceinline__ unsigned short tbf_lo(float x) {
    unsigned u = __float_as_uint(x);
    float r = x - __uint_as_float(u & 0xFFFF0000u);
    return (unsigned short)(__float_as_uint(r) >> 16);
}
__device__ __forceinline__ unsigned packhi(unsigned u0, unsigned u1) {
#if __has_builtin(__builtin_amdgcn_perm)
    return __builtin_amdgcn_perm(u1, u0, 0x07060302u);
#else
    return (u1 & 0xFFFF0000u) | (u0 >> 16);
#endif
}
__device__ __forceinline__ void tsplit8(const float* v, unsigned* hw, unsigned* lw) {
#pragma unroll
    for (int t = 0; t < 4; ++t) {
        unsigned u0 = __float_as_uint(v[2 * t]);
        unsigned u1 = __float_as_uint(v[2 * t + 1]);
        float r0 = v[2 * t]     - __uint_as_float(u0 & 0xFFFF0000u);
        float r1 = v[2 * t + 1] - __uint_as_float(u1 & 0xFFFF0000u);
        hw[t] = packhi(u0, u1);
        lw[t] = packhi(__float_as_uint(r0), __float_as_uint(r1));
    }
}

#if __has_builtin(__builtin_amdgcn_global_load_lds)
#define HAVE_GLDS 1
__device__ __forceinline__ void gld16(const ushort_t* g, ushort_t* l) {
    __builtin_amdgcn_global_load_lds(
        (const __attribute__((address_space(1))) unsigned int*)g,
        (__attribute__((address_space(3))) unsigned int*)l, 16, 0, 0);
}
#else
#define HAVE_GLDS 0
#endif

// ---------------- LN stats (for fp32 intermediates) ----------------
__global__ __launch_bounds__(256) void ln_stats_kernel(
    const float* __restrict__ src, float* __restrict__ mu,
    float* __restrict__ rs, int rows) {
    int row = blockIdx.x * 4 + (threadIdx.x >> 6);
    int lane = threadIdx.x & 63;
    if (row >= rows) return;
    const float* p = src + (size_t)row * 384;
    float s = 0.f, sq = 0.f;
#pragma unroll
    for (int i = 0; i < 6; ++i) {
        float v = p[lane + 64 * i];
        s += v; sq += v * v;
    }
#pragma unroll
    for (int off = 32; off > 0; off >>= 1) {
        s += __shfl_down(s, off);
        sq += __shfl_down(sq, off);
    }
    if (lane == 0) {
        float m = s / 384.f;
        float var = sq / 384.f - m * m;
        mu[row] = m;
        rs[row] = rsqrtf(var + 1e-6f);
    }
}

// ---------------- fused LN stats + raw hi/lo split (for raw inputs) ----------------
__global__ __launch_bounds__(256) void lnsplit_kernel(
    const float* __restrict__ src, float* __restrict__ mu,
    float* __restrict__ rs, ushort_t* __restrict__ dh,
    ushort_t* __restrict__ dl, int rows) {
    int row = blockIdx.x * 4 + (threadIdx.x >> 6);
    int lane = threadIdx.x & 63;
    if (row >= rows) return;
    const float* p = src + (size_t)row * 384;
    float v[6];
    float s = 0.f, sq = 0.f;
#pragma unroll
    for (int i = 0; i < 6; ++i) {
        v[i] = p[lane + 64 * i];
        s += v[i]; sq += v[i] * v[i];
    }
#pragma unroll
    for (int i = 0; i < 6; ++i) {
        dh[(size_t)row * 384 + lane + 64 * i] = tbf_hi(v[i]);
        dl[(size_t)row * 384 + lane + 64 * i] = tbf_lo(v[i]);
    }
#pragma unroll
    for (int off = 32; off > 0; off >>= 1) {
        s += __shfl_down(s, off);
        sq += __shfl_down(sq, off);
    }
    if (lane == 0) {
        float m = s / 384.f;
        float var = sq / 384.f - m * m;
        mu[row] = m;
        rs[row] = rsqrtf(var + 1e-6f);
    }
}

// ---------------- weight prep ----------------
struct WprepTab {
    const float* src[10]; const float* g[10];
    ushort_t* dh[10]; ushort_t* dl[10];
    float scale[10]; int N[10];
};
__global__ __launch_bounds__(256) void wprep_all(WprepTab t) {
    int e = blockIdx.y;
    int N = t.N[e];
    int idx = blockIdx.x * 256 + threadIdx.x;
    if (idx >= N * 384) return;
    int n = idx / 384, k = idx % 384;
    float x = t.src[e][(size_t)k * N + n] * t.scale[e];
    if (t.g[e]) x *= t.g[e][k];
    t.dh[e][idx] = tbf_hi(x);
    t.dl[e][idx] = tbf_lo(x);
}

// ---------------- cm/cb vectors (LN fold) + b67 ----------------
struct CmcbTab {
    const float* src[5]; const float* g[5]; const float* lb[5]; const float* badd[5];
    float* cm[5]; float* cb[5]; float scale[5]; int N[5];
};
__global__ __launch_bounds__(256) void cmcb_all(CmcbTab t) {
    int e = blockIdx.y;
    int N = t.N[e];
    int c = blockIdx.x * 4 + (threadIdx.x >> 6);
    int lane = threadIdx.x & 63;
    if (c >= N) return;
    float s1 = 0.f, s2 = 0.f;
    const float* gp = t.g[e];
#pragma unroll
    for (int i = 0; i < 6; ++i) {
        int k = lane + 64 * i;
        float w = t.src[e][(size_t)k * N + c];
        if (gp) s1 += gp[k] * w;
        s2 += t.lb[e][k] * w;
    }
#pragma unroll
    for (int off = 32; off > 0; off >>= 1) {
        s1 += __shfl_down(s1, off);
        s2 += __shfl_down(s2, off);
    }
    if (lane == 0) {
        if (t.cm[e]) t.cm[e][c] = -t.scale[e] * s1;
        float v = t.scale[e] * s2;
        if (t.badd[e]) v += t.badd[e][c];
        t.cb[e][c] = v;
    }
}

// ---------------- split-bf16 MFMA GEMM, 384-col slot outputs ----------------
struct Slot {
    const float* bias; const float* cm; const float* cb;
    float* f32o; ushort_t* oh; ushort_t* ol;
    int mode; int kvsh;
};
struct GemmCfg { const float* muA; const float* rsA; Slot s[4]; };

template <int TM, int TN, int ASPLIT, int XSWZ>
__global__ __launch_bounds__(256) void gemm_k(
    const float* __restrict__ Af,
    const ushort_t* __restrict__ Ah, const ushort_t* __restrict__ Al,
    const ushort_t* __restrict__ Bh, const ushort_t* __restrict__ Bl,
    GemmCfg cfg) {
    constexpr int MI = TM / 64;
    constexpr int NI = TN / 16;
    constexpr int AR = TM / 32, BR = TN / 32;
    __shared__ __align__(16) ushort_t Alds[2][TM * 64];
    __shared__ __align__(16) ushort_t Blds[2][TN * 64];
    int bx = blockIdx.x, by = blockIdx.y;
    if (XSWZ) {
        int gx = gridDim.x;
        int nwg = gx * gridDim.y;
        int lin = by * gx + bx;
        int cpx = nwg >> 3;
        lin = (lin & 7) * cpx + (lin >> 3);
        by = lin / gx;
        bx = lin - by * gx;
    }
    int m0 = by * TM, n0 = bx * TN;
    int tid = threadIdx.x;
    int w = tid >> 6, lane = tid & 63;
    int j = lane & 15, kg = lane >> 4;
    int srow = tid >> 3, sk16 = tid & 7;
    f32x4 acc[MI][NI];
#pragma unroll
    for (int mi = 0; mi < MI; ++mi)
#pragma unroll
        for (int ni = 0; ni < NI; ++ni)
#pragma unroll
            for (int r = 0; r < 4; ++r) acc[mi][ni][r] = 0.f;

    for (int ks = 0; ks < 6; ++ks) {
        __syncthreads();
#if HAVE_GLDS
        if (ASPLIT) {
#pragma unroll
            for (int i = 0; i < TM / 32; ++i) {
                int lrow = w * (TM / 4) + i * 8 + (lane >> 3);
                int cc = (lane & 7) ^ (lrow & 7);
                size_t ga = (size_t)(m0 + lrow) * 384 + ks * 64 + cc * 8;
                gld16(Ah + ga, &Alds[0][(w * (TM / 4) + i * 8) * 64]);
                gld16(Al + ga, &Alds[1][(w * (TM / 4) + i * 8) * 64]);
            }
#pragma unroll
            for (int i = 0; i < TN / 32; ++i) {
                int lrow = w * (TN / 4) + i * 8 + (lane >> 3);
                int cc = (lane & 7) ^ (lrow & 7);
                size_t gb = (size_t)(n0 + lrow) * 384 + ks * 64 + cc * 8;
                gld16(Bh + gb, &Blds[0][(w * (TN / 4) + i * 8) * 64]);
                gld16(Bl + gb, &Blds[1][(w * (TN / 4) + i * 8) * 64]);
            }
        } else
#endif
        {
            int kbase = ks * 64 + sk16 * 8;
#pragma unroll
            for (int rnd = 0; rnd < AR; ++rnd) {
                int row = srow + rnd * 32;
                int off = (row << 6) + ((sk16 ^ (row & 7)) << 3);
                if (ASPLIT) {
                    size_t ga = (size_t)(m0 + row) * 384 + kbase;
                    *(bf16x8*)&Alds[0][off] = *(const bf16x8*)(Ah + ga);
                    *(bf16x8*)&Alds[1][off] = *(const bf16x8*)(Al + ga);
                } else {
                    const float* ap = Af + (size_t)(m0 + row) * 384 + kbase;
                    float v[8];
                    *(float4*)v = *(const float4*)ap;
                    *(float4*)(v + 4) = *(const float4*)(ap + 4);
                    unsigned hw[4], lw[4];
                    tsplit8(v, hw, lw);
                    *(uint4*)&Alds[0][off] = *(uint4*)hw;
                    *(uint4*)&Alds[1][off] = *(uint4*)lw;
                }
            }
#pragma unroll
            for (int rnd = 0; rnd < BR; ++rnd) {
                int row = srow + rnd * 32;
                int off = (row << 6) + ((sk16 ^ (row & 7)) << 3);
                size_t gb = (size_t)(n0 + row) * 384 + kbase;
                *(bf16x8*)&Blds[0][off] = *(const bf16x8*)(Bh + gb);
                *(bf16x8*)&Blds[1][off] = *(const bf16x8*)(Bl + gb);
            }
        }
        __syncthreads();
#pragma unroll
        for (int kf = 0; kf < 2; ++kf) {
            bf16x8 afh[MI], afl[MI], bfh[NI], bfl[NI];
#pragma unroll
            for (int mi = 0; mi < MI; ++mi) {
                int row = w * (TM / 4) + mi * 16 + j;
                int off = (row << 6) + ((((kf << 2) | kg) ^ (row & 7)) << 3);
                afh[mi] = *(const bf16x8*)&Alds[0][off];
                afl[mi] = *(const bf16x8*)&Alds[1][off];
            }
#pragma unroll
            for (int ni = 0; ni < NI; ++ni) {
                int col = ni * 16 + j;
                int off = (col << 6) + ((((kf << 2) | kg) ^ (col & 7)) << 3);
                bfh[ni] = *(const bf16x8*)&Blds[0][off];
                bfl[ni] = *(const bf16x8*)&Blds[1][off];
            }
#pragma unroll
            for (int mi = 0; mi < MI; ++mi)
#pragma unroll
                for (int ni = 0; ni < NI; ++ni) {
                    acc[mi][ni] = MFMA(afh[mi], bfh[ni], acc[mi][ni], 0, 0, 0);
                    acc[mi][ni] = MFMA(afh[mi], bfl[ni], acc[mi][ni], 0, 0, 0);
                    acc[mi][ni] = MFMA(afl[mi], bfh[ni], acc[mi][ni], 0, 0, 0);
                }
        }
    }
    int slot = n0 / 384;
    Slot sl = cfg.s[slot];
    int cb0 = n0 % 384;
#pragma unroll
    for (int mi = 0; mi < MI; ++mi)
#pragma unroll
        for (int ni = 0; ni < NI; ++ni)
#pragma unroll
            for (int r = 0; r < 4; ++r) {
                int row = m0 + w * (TM / 4) + mi * 16 + kg * 4 + r;
                int c2 = cb0 + ni * 16 + j;
                float v = acc[mi][ni][r];
                if (sl.cm) {
                    float rss = cfg.rsA[row];
                    v = rss * v + rss * cfg.muA[row] * sl.cm[c2] + sl.cb[c2];
                }
                if (sl.bias) v += sl.bias[c2];
                if (sl.mode == 0) {
                    sl.f32o[(size_t)row * 384 + c2] = v;
                } else if (sl.mode == 1) {
                    sl.f32o[(size_t)row * 384 + c2] = tanhf(v);
                } else if (sl.mode == 2) {
                    sl.oh[(size_t)row * 384 + c2] = tbf_hi(v);
                    sl.ol[(size_t)row * 384 + c2] = tbf_lo(v);
                } else if (sl.mode == 4) {
                    size_t o = (size_t)c2 * 384 + row;
                    sl.oh[o] = tbf_hi(v);
                    sl.ol[o] = tbf_lo(v);
                } else {
                    int bb = row >> sl.kvsh;
                    int key = row & ((1 << sl.kvsh) - 1);
                    size_t o = (((size_t)bb * 384 + c2) << sl.kvsh) + key;
                    sl.oh[o] = tbf_hi(v);
                    sl.ol[o] = tbf_lo(v);
                }
            }
}

// ---------------- big-tile GEMM for the kv projections ----------------
// TM=128, TN=128, 512 threads (8 waves 2m x 4n), single-buffer 64KB LDS.
template <int XSWZ>
__global__ __launch_bounds__(512, 4) void gemm_big(
    const ushort_t* __restrict__ Ah, const ushort_t* __restrict__ Al,
    const ushort_t* __restrict__ Bh, const ushort_t* __restrict__ Bl,
    GemmCfg cfg) {
    __shared__ __align__(16) ushort_t Alds[2][128 * 64];
    __shared__ __align__(16) ushort_t Blds[2][128 * 64];
    int bx = blockIdx.x, by = blockIdx.y;
    if (XSWZ) {
        int gx = gridDim.x;
        int nwg = gx * gridDim.y;
        int lin = by * gx + bx;
        int cpx = nwg >> 3;
        lin = (lin & 7) * cpx + (lin >> 3);
        by = lin / gx;
        bx = lin - by * gx;
    }
    int m0 = by * 128, n0 = bx * 128;
    int tid = threadIdx.x;
    int w = tid >> 6, lane = tid & 63;
    int wm = w >> 2, wn = w & 3;
    int j = lane & 15, kg = lane >> 4;
    f32x4 acc[4][2];
#pragma unroll
    for (int mi = 0; mi < 4; ++mi)
#pragma unroll
        for (int ni = 0; ni < 2; ++ni)
#pragma unroll
            for (int r = 0; r < 4; ++r) acc[mi][ni][r] = 0.f;

    for (int ks = 0; ks < 6; ++ks) {
        __syncthreads();
        // stage: 1024 16B-chunks per half per matrix; wave w, issue i owns
        // chunks [(i*8+w)*64 .. +64). LDS dest linear; global src inverse-swizzled.
#pragma unroll
        for (int i = 0; i < 2; ++i) {
            int cbase = (i * 8 + w) * 64;
            int chunk = cbase + lane;
            int lrow = chunk >> 3;
            int cc = (chunk & 7) ^ (lrow & 7);
            size_t ga = (size_t)(m0 + lrow) * 384 + ks * 64 + cc * 8;
            size_t gb = (size_t)(n0 + lrow) * 384 + ks * 64 + cc * 8;
#if HAVE_GLDS
            gld16(Ah + ga, &Alds[0][cbase * 8]);
            gld16(Al + ga, &Alds[1][cbase * 8]);
            gld16(Bh + gb, &Blds[0][cbase * 8]);
            gld16(Bl + gb, &Blds[1][cbase * 8]);
#else
            *(bf16x8*)&Alds[0][chunk * 8] = *(const bf16x8*)(Ah + ga);
            *(bf16x8*)&Alds[1][chunk * 8] = *(const bf16x8*)(Al + ga);
            *(bf16x8*)&Blds[0][chunk * 8] = *(const bf16x8*)(Bh + gb);
            *(bf16x8*)&Blds[1][chunk * 8] = *(const bf16x8*)(Bl + gb);
#endif
        }
        __syncthreads();
#pragma unroll
        for (int kf = 0; kf < 2; ++kf) {
            bf16x8 afh[4], afl[4], bfh[2], bfl[2];
#pragma unroll
            for (int mi = 0; mi < 4; ++mi) {
                int row = wm * 64 + mi * 16 + j;
                int off = (row << 6) + ((((kf << 2) | kg) ^ (row & 7)) << 3);
                afh[mi] = *(const bf16x8*)&Alds[0][off];
                afl[mi] = *(const bf16x8*)&Alds[1][off];
            }
#pragma unroll
            for (int ni = 0; ni < 2; ++ni) {
                int col = wn * 32 + ni * 16 + j;
                int off = (col << 6) + ((((kf << 2) | kg) ^ (col & 7)) << 3);
                bfh[ni] = *(const bf16x8*)&Blds[0][off];
                bfl[ni] = *(const bf16x8*)&Blds[1][off];
            }
#pragma unroll
            for (int mi = 0; mi < 4; ++mi)
#pragma unroll
                for (int ni = 0; ni < 2; ++ni) {
                    acc[mi][ni] = MFMA(afh[mi], bfh[ni], acc[mi][ni], 0, 0, 0);
                    acc[mi][ni] = MFMA(afh[mi], bfl[ni], acc[mi][ni], 0, 0, 0);
                    acc[mi][ni] = MFMA(afl[mi], bfh[ni], acc[mi][ni], 0, 0, 0);
                }
        }
    }
    int slot = n0 / 384;
    Slot sl = cfg.s[slot];
    int cb0 = n0 % 384;
#pragma unroll
    for (int mi = 0; mi < 4; ++mi)
#pragma unroll
        for (int ni = 0; ni < 2; ++ni) {
            int row0 = m0 + wm * 64 + mi * 16 + kg * 4;
            int c2 = cb0 + wn * 32 + ni * 16 + j;
            float v[4];
#pragma unroll
            for (int r = 0; r < 4; ++r) {
                float x = acc[mi][ni][r];
                if (sl.cm) {
                    float rss = cfg.rsA[row0 + r];
                    x = rss * x + rss * cfg.muA[row0 + r] * sl.cm[c2] + sl.cb[c2];
                }
                v[r] = x;
            }
            if (sl.mode == 2) {
#pragma unroll
                for (int r = 0; r < 4; ++r) {
                    sl.oh[(size_t)(row0 + r) * 384 + c2] = tbf_hi(v[r]);
                    sl.ol[(size_t)(row0 + r) * 384 + c2] = tbf_lo(v[r]);
                }
            } else {
                // mode 3: V^T, consecutive r = consecutive keys -> 8B stores
                int bb = row0 >> sl.kvsh;
                int key = row0 & ((1 << sl.kvsh) - 1);
                size_t o = (((size_t)bb * 384 + c2) << sl.kvsh) + key;
                us4 h4, l4;
#pragma unroll
                for (int r = 0; r < 4; ++r) { h4[r] = tbf_hi(v[r]); l4[r] = tbf_lo(v[r]); }
                *(us4*)(sl.oh + o) = h4;
                *(us4*)(sl.ol + o) = l4;
            }
        }
}

// ---------------- MFMA flash attention, key-chunked, split-bf16 ----------------
template <int HD, int DPAD, int NW, int GAUSS, int FINAL>
__global__ __launch_bounds__(64 * NW) void attn_k(
    const ushort_t* __restrict__ Qh, const ushort_t* __restrict__ Ql,
    const ushort_t* __restrict__ Kh, const ushort_t* __restrict__ Kl,
    const ushort_t* __restrict__ Vth, const ushort_t* __restrict__ Vtl,
    const float* __restrict__ PT,
    ushort_t* __restrict__ Xh, ushort_t* __restrict__ Xl,
    float* __restrict__ Opart, float* __restrict__ ML,
    int kvsh, int nch, int NS, int nh) {
    constexpr int KS = DPAD / 32;
    constexpr int NSUB = HD / 16;
    constexpr int C8 = DPAD / 8;
    constexpr int NT = 64 * NW;
    __shared__ __align__(16) ushort_t Ksh[2][32][DPAD + 8];
    __shared__ __align__(16) ushort_t Vsh[2][HD][40];
    __shared__ __align__(16) ushort_t Psh[NW][2][16][40];
    __shared__ float ptbl[GAUSS ? 64 : 1];
    int b = blockIdx.z, h = blockIdx.y, chunk = blockIdx.x;
    int tid = threadIdx.x;
    int w = tid >> 6, lane = tid & 63;
    int l15 = lane & 15, kg = lane >> 4;

    bf16x8 qf[2][KS];
    {
        size_t qa = (size_t)(b * 64 + w * 16 + l15) * 384 + h * HD + kg * 8;
#pragma unroll
        for (int ks = 0; ks < KS; ++ks) {
            if (ks * 32 + kg * 8 < HD) {
                qf[0][ks] = *(const bf16x8*)(Qh + qa + ks * 32);
                qf[1][ks] = *(const bf16x8*)(Ql + qa + ks * 32);
            } else {
                qf[0][ks] = bf16x8{};
                qf[1][ks] = bf16x8{};
            }
        }
    }
    if (GAUSS) {
        if (tid < 64) ptbl[tid] = PT[b * 64 + tid];
    }
    f32x4 oacc[NSUB];
#pragma unroll
    for (int ns = 0; ns < NSUB; ++ns)
#pragma unroll
        for (int r = 0; r < 4; ++r) oacc[ns][r] = 0.f;
    float m_run[4], l_run[4];
#pragma unroll
    for (int r = 0; r < 4; ++r) { m_run[r] = -1e30f; l_run[r] = 0.f; }

    int kbase0 = chunk * nch;
    for (int t = 0; t < nch; t += 32) {
        int n0 = kbase0 + t;
        __syncthreads();
        for (int i = tid; i < 2 * 32 * C8; i += NT) {
            int hl = i / (32 * C8);
            int rem = i - hl * 32 * C8;
            int key = rem / C8, c = rem % C8;
            bf16x8 v;
            if (c * 8 < HD) {
                const ushort_t* src = (hl ? Kl : Kh) +
                    ((size_t)((b << kvsh) + n0 + key)) * 384 + h * HD + c * 8;
                v = *(const bf16x8*)src;
            } else {
                v = bf16x8{};
            }
            *(bf16x8*)&Ksh[hl][key][c * 8] = v;
        }
        for (int i = tid; i < 2 * HD * 4; i += NT) {
            int hl = i / (HD * 4);
            int rem = i - hl * HD * 4;
            int dim = rem >> 2, c = rem & 3;
            const ushort_t* src = (hl ? Vtl : Vth) +
                (((size_t)(b * 384 + h * HD + dim)) << kvsh) + n0 + c * 8;
            *(bf16x8*)&Vsh[hl][dim][c * 8] = *(const bf16x8*)src;
        }
        __syncthreads();

        f32x4 shh[2], slh[2], shl[2];
#pragma unroll
        for (int sub = 0; sub < 2; ++sub)
#pragma unroll
            for (int r = 0; r < 4; ++r) { shh[sub][r] = 0.f; slh[sub][r] = 0.f; shl[sub][r] = 0.f; }
#pragma unroll
        for (int sub = 0; sub < 2; ++sub)
#pragma unroll
            for (int ks = 0; ks < KS; ++ks) {
                bf16x8 kh8 = *(const bf16x8*)&Ksh[0][sub * 16 + l15][ks * 32 + kg * 8];
                bf16x8 kl8 = *(const bf16x8*)&Ksh[1][sub * 16 + l15][ks * 32 + kg * 8];
                shh[sub] = MFMA(qf[0][ks], kh8, shh[sub], 0, 0, 0);
                slh[sub] = MFMA(qf[1][ks], kh8, slh[sub], 0, 0, 0);
                shl[sub] = MFMA(qf[0][ks], kl8, shl[sub], 0, 0, 0);
            }
        f32x4 s[2];
#pragma unroll
        for (int sub = 0; sub < 2; ++sub)
#pragma unroll
            for (int r = 0; r < 4; ++r)
                s[sub][r] = shh[sub][r] + slh[sub][r] + shl[sub][r];
        if (GAUSS) {
            int win = n0 >> 7;
#pragma unroll
            for (int sub = 0; sub < 2; ++sub) {
                float wpos = (float)((n0 + sub * 16 + l15) & 127);
#pragma unroll
                for (int r = 0; r < 4; ++r) {
                    float ptv = ptbl[((w * 16 + kg * 4 + r) * 8 + win) & 63];
                    float d = wpos - ptv;
                    s[sub][r] *= __expf(d * d * (-1.0f / 18.0f));
                }
            }
        }
#pragma unroll
        for (int r = 0; r < 4; ++r) {
            float v = fmaxf(s[0][r], s[1][r]);
            v = fmaxf(v, __shfl_xor(v, 1));
            v = fmaxf(v, __shfl_xor(v, 2));
            v = fmaxf(v, __shfl_xor(v, 4));
            v = fmaxf(v, __shfl_xor(v, 8));
            float mnew = fmaxf(m_run[r], v);
            float alpha = __expf(m_run[r] - mnew);
            m_run[r] = mnew;
            float p0 = __expf(s[0][r] - mnew);
            float p1 = __expf(s[1][r] - mnew);
            float ps = p0 + p1;
            ps += __shfl_xor(ps, 1);
            ps += __shfl_xor(ps, 2);
            ps += __shfl_xor(ps, 4);
            ps += __shfl_xor(ps, 8);
            l_run[r] = l_run[r] * alpha + ps;
#pragma unroll
            for (int ns = 0; ns < NSUB; ++ns) oacc[ns][r] *= alpha;
            Psh[w][0][kg * 4 + r][l15] = tbf_hi(p0);
            Psh[w][1][kg * 4 + r][l15] = tbf_lo(p0);
            Psh[w][0][kg * 4 + r][16 + l15] = tbf_hi(p1);
            Psh[w][1][kg * 4 + r][16 + l15] = tbf_lo(p1);
        }
        bf16x8 pfh = *(const bf16x8*)&Psh[w][0][l15][kg * 8];
        bf16x8 pfl = *(const bf16x8*)&Psh[w][1][l15][kg * 8];
#pragma unroll
        for (int ns = 0; ns < NSUB; ++ns) {
            bf16x8 vh8 = *(const bf16x8*)&Vsh[0][ns * 16 + l15][kg * 8];
            bf16x8 vl8 = *(const bf16x8*)&Vsh[1][ns * 16 + l15][kg * 8];
            oacc[ns] = MFMA(pfh, vh8, oacc[ns], 0, 0, 0);
            oacc[ns] = MFMA(pfl, vh8, oacc[ns], 0, 0, 0);
            oacc[ns] = MFMA(pfh, vl8, oacc[ns], 0, 0, 0);
        }
    }
    if (FINAL) {
#pragma unroll
        for (int ns = 0; ns < NSUB; ++ns)
#pragma unroll
            for (int r = 0; r < 4; ++r) {
                float val = oacc[ns][r] / l_run[r];
                size_t o = (size_t)(b * 64 + w * 16 + kg * 4 + r) * 384 +
                           h * HD + ns * 16 + l15;
                Xh[o] = tbf_hi(val);
                Xl[o] = tbf_lo(val);
            }
    } else {
#pragma unroll
        for (int r = 0; r < 4; ++r) {
            int rq = w * 16 + kg * 4 + r;
            size_t Pidx = ((size_t)((b * nh + h) * 64 + rq)) * NS + chunk;
#pragma unroll
            for (int ns = 0; ns < NSUB; ++ns)
                Opart[Pidx * HD + ns * 16 + l15] = oacc[ns][r];
            if (l15 == 0) {
                ML[Pidx * 2] = m_run[r];
                ML[Pidx * 2 + 1] = l_run[r];
            }
        }
    }
}

// ---------------- flash combine ----------------
template <int HD>
__global__ __launch_bounds__(256) void comb_k(
    const float* __restrict__ Opart, const float* __restrict__ ML,
    ushort_t* __restrict__ Xh, ushort_t* __restrict__ Xl,
    int NS, int nh) {
    int gw = blockIdx.x * 4 + (threadIdx.x >> 6);
    int lane = threadIdx.x & 63;
    if (gw >= 2048 * nh) return;
    int r_ = gw / nh, h = gw % nh;
    int b = r_ >> 6, rq = r_ & 63;
    size_t Pb = ((size_t)((b * nh + h) * 64 + rq)) * NS;
    float M = -1e30f;
    for (int c = 0; c < NS; ++c) M = fmaxf(M, ML[(Pb + c) * 2]);
    float wgt[8];
    float L = 0.f;
    for (int c = 0; c < NS; ++c) {
        wgt[c] = __expf(ML[(Pb + c) * 2] - M);
        L += wgt[c] * ML[(Pb + c) * 2 + 1];
    }
    float invL = 1.f / L;
    for (int d = lane; d < HD; d += 64) {
        float o = 0.f;
        for (int c = 0; c < NS; ++c) o += wgt[c] * Opart[(Pb + c) * HD + d];
        o *= invL;
        size_t xo = (size_t)r_ * 384 + h * HD + d;
        Xh[xo] = tbf_hi(o);
        Xl[xo] = tbf_lo(o);
    }
}

// ---------------- p_t head ----------------
__global__ __launch_bounds__(256) void pt_kernel(
    const float* __restrict__ T, const float* __restrict__ vpw,
    const float* __restrict__ vpb, float* __restrict__ pt, int rows) {
    int row = blockIdx.x * 4 + (threadIdx.x >> 6);
    int lane = threadIdx.x & 63;
    if (row >= rows) return;
    const float* p = T + (size_t)row * 384;
    float s = 0.f;
#pragma unroll
    for (int i = 0; i < 6; ++i) s += p[lane + 64 * i] * vpw[lane + 64 * i];
#pragma unroll
    for (int off = 32; off > 0; off >>= 1) s += __shfl_down(s, off);
    if (lane == 0) {
        float x = s + vpb[0];
        pt[row] = 128.f / (1.f + __expf(-x));
    }
}

extern "C" void kernel_launch(void* const* d_in, const int* in_sizes, int n_in,
                              void* d_out, int out_size, void* d_ws, size_t ws_size,
                              hipStream_t stream) {
    const float* q       = (const float*)d_in[0];
    const float* kv      = (const float*)d_in[1];
    const float* Wq      = (const float*)d_in[2];
    const float* Wkv     = (const float*)d_in[3];
    const float* Wproj   = (const float*)d_in[4];
    const float* bproj   = (const float*)d_in[5];
    const float* Wp_w    = (const float*)d_in[6];
    const float* Wp_b    = (const float*)d_in[7];
    const float* vp_w    = (const float*)d_in[8];
    const float* vp_b    = (const float*)d_in[9];
    const float* qpos_w  = (const float*)d_in[10];
    const float* qpos_b  = (const float*)d_in[11];
    const float* ca1_Wq  = (const float*)d_in[12];
    const float* ca1_Wkv = (const float*)d_in[13];
    const float* ca1_Wp  = (const float*)d_in[14];
    const float* ca1_bp  = (const float*)d_in[15];
    const float* ca2_Wq  = (const float*)d_in[16];
    const float* ca2_Wkv = (const float*)d_in[17];
    const float* ca2_Wp  = (const float*)d_in[18];
    const float* ca2_bp  = (const float*)d_in[19];
    const float* lnq1_g  = (const float*)d_in[20];
    const float* lnq1_b  = (const float*)d_in[21];
    const float* lnkv1_g = (const float*)d_in[22];
    const float* lnkv1_b = (const float*)d_in[23];
    const float* lnq2_g  = (const float*)d_in[24];
    const float* lnq2_b  = (const float*)d_in[25];
    const float* lnkv2_g = (const float*)d_in[26];
    const float* lnkv2_b = (const float*)d_in[27];
    float* out = (float*)d_out;

    const float SC_CA = 0.07216878364870323f;   // 192^-0.5
    const float SC_MA = 0.14433756729740643f;   // 48^-0.5

    float* F = (float*)d_ws;
    float* R0 = F;    F += 786432;
    float* R1 = F;    F += 786432;
    float* MUq = F;   F += 2048;
    float* RSq = F;   F += 2048;
    float* MUkv = F;  F += 32768;
    float* RSkv = F;  F += 32768;
    float* MUpa = F;  F += 2048;
    float* RSpa = F;  F += 2048;
    float* MUpb = F;  F += 2048;
    float* RSpb = F;  F += 2048;
    float* PTb = F;   F += 2048;
    float* CM = F;    F += 2304;
    float* CB = F;    F += 2688;
    float* OP = F;    F += 6291456;
    float* MLb = F;   F += 262144;
    ushort_t* U = (ushort_t*)F;
    ushort_t* WB1h = U; U += 589824;
    ushort_t* WB1l = U; U += 589824;
    ushort_t* WB5h = U; U += 589824;   // [ca2_K | ca2_V | main_K | main_V] weights, 1536x384
    ushort_t* WB5l = U; U += 589824;
    ushort_t* W2h = U;  U += 147456;
    ushort_t* W2l = U;  U += 147456;
    ushort_t* W3h = U;  U += 147456;
    ushort_t* W3l = U;  U += 147456;
    ushort_t* W4h = U;  U += 147456;
    ushort_t* W4l = U;  U += 147456;
    ushort_t* W67h = U; U += 147456;
    ushort_t* W67l = U; U += 147456;
    ushort_t* W7h = U;  U += 147456;
    ushort_t* W7l = U;  U += 147456;
    ushort_t* W10h = U; U += 147456;
    ushort_t* W10l = U; U += 147456;
    ushort_t* Qch = U;  U += 786432;
    ushort_t* Qcl = U;  U += 786432;
    ushort_t* Qmh = U;  U += 786432;
    ushort_t* Qml = U;  U += 786432;
    ushort_t* Xh = U;   U += 786432;
    ushort_t* Xl = U;   U += 786432;
    ushort_t* K1h = U;  U += 786432;
    ushort_t* K1l = U;  U += 786432;
    ushort_t* V1h = U;  U += 786432;
    ushort_t* V1l = U;  U += 786432;
    ushort_t* K2h = U;  U += 12582912;
    ushort_t* K2l = U;  U += 12582912;
    ushort_t* V2h = U;  U += 12582912;
    ushort_t* V2l = U;  U += 12582912;
    ushort_t* Qsh = U;  U += 786432;
    ushort_t* Qsl = U;  U += 786432;
    ushort_t* KVsh = U; U += 12582912;
    ushort_t* KVsl = U; U += 12582912;
    // ALIAS: main-attn K/V reuse the CA2 K/V region (dead after CA2 attention).
    ushort_t* Kmh = K2h;
    ushort_t* Kml = K2l;
    ushort_t* Vmh = V2h;
    ushort_t* Vml = V2l;

    dim3 blk(256);

    // fused stats + raw split on inputs
    lnsplit_kernel<<<512, blk, 0, stream>>>(q, MUq, RSq, Qsh, Qsl, 2048);
    lnsplit_kernel<<<8192, blk, 0, stream>>>(kv, MUkv, RSkv, KVsh, KVsl, 32768);

    // weight prep
    WprepTab wt{};
    const float* wsrc[10] = {qpos_w, ca1_Wkv, Wq, ca2_Wkv, Wkv,
                             ca1_Wq, ca1_Wp, ca2_Wq, Wp_w, Wproj};
    const float* wg[10] = {nullptr, lnkv1_g, nullptr, lnkv2_g, nullptr,
                           lnq1_g, nullptr, lnq2_g, nullptr, nullptr};
    ushort_t* wdh[10] = {WB1h, WB1h + 384 * 384, WB1h + 1152 * 384,
                         WB5h, WB5h + 768 * 384, W2h, W3h, W4h, W7h, W10h};
    ushort_t* wdl[10] = {WB1l, WB1l + 384 * 384, WB1l + 1152 * 384,
                         WB5l, WB5l + 768 * 384, W2l, W3l, W4l, W7l, W10l};
    float wsc[10] = {1.f, 1.f, SC_MA, 1.f, 1.f, SC_CA, 1.f, SC_CA, 1.f, 1.f};
    int wn[10] = {384, 768, 384, 768, 768, 384, 384, 384, 384, 384};
    for (int i = 0; i < 10; ++i) {
        wt.src[i] = wsrc[i]; wt.g[i] = wg[i]; wt.dh[i] = wdh[i];
        wt.dl[i] = wdl[i]; wt.scale[i] = wsc[i]; wt.N[i] = wn[i];
    }
    wprep_all<<<dim3(1152, 10), blk, 0, stream>>>(wt);

    // cm/cb (LN folds) + b67
    CmcbTab ct{};
    const float* csrc[5] = {ca1_Wq, ca1_Wkv, ca2_Wq, ca2_Wkv, Wp_w};
    const float* cg[5] = {lnq1_g, lnkv1_g, lnq2_g, lnkv2_g, nullptr};
    const float* cl[5] = {lnq1_b, lnkv1_b, lnq2_b, lnkv2_b, ca2_bp};
    const float* cbad[5] = {nullptr, nullptr, nullptr, nullptr, Wp_b};
    float* ccm[5] = {CM, CM + 384, CM + 1152, CM + 1536, nullptr};
    float* ccb[5] = {CB, CB + 384, CB + 1152, CB + 1536, CB + 2304};
    float csc[5] = {SC_CA, 1.f, SC_CA, 1.f, 1.f};
    int cn[5] = {384, 768, 384, 768, 384};
    for (int i = 0; i < 5; ++i) {
        ct.src[i] = csrc[i]; ct.g[i] = cg[i]; ct.lb[i] = cl[i]; ct.badd[i] = cbad[i];
        ct.cm[i] = ccm[i]; ct.cb[i] = ccb[i]; ct.scale[i] = csc[i]; ct.N[i] = cn[i];
    }
    cmcb_all<<<dim3(192, 5), blk, 0, stream>>>(ct);

    // W67 = ca2_Wp @ Wp_w  (transposed-split output for B-use)
    GemmCfg gW{};
    gW.s[0] = {nullptr, nullptr, nullptr, nullptr, W67h, W67l, 4, 0};
    gemm_k<64, 64, 0, 0><<<dim3(6, 6), blk, 0, stream>>>(ca2_Wp, nullptr, nullptr, W7h, W7l, gW);

    // G5a: A=kv split [32768], W = [ca2_K | ca2_V], 128x128 big tile, XCD swizzle
    GemmCfg g5a{};
    g5a.muA = MUkv; g5a.rsA = RSkv;
    g5a.s[0] = {nullptr, CM + 1536, CB + 1536, nullptr, K2h, K2l, 2, 0};
    g5a.s[1] = {nullptr, CM + 1920, CB + 1920, nullptr, V2h, V2l, 3, 10};
    gemm_big<1><<<dim3(6, 256), dim3(512), 0, stream>>>(KVsh, KVsl, WB5h, WB5l, g5a);

    // G1: A=q split [2048], W = [qpos | ca1_K (LN q) | ca1_V (LN q) | mainQ]
    GemmCfg g1{};
    g1.muA = MUq; g1.rsA = RSq;
    g1.s[0] = {qpos_b, nullptr, nullptr, R0, nullptr, nullptr, 0, 0};
    g1.s[1] = {nullptr, CM + 384, CB + 384, nullptr, K1h, K1l, 2, 0};
    g1.s[2] = {nullptr, CM + 768, CB + 768, nullptr, V1h, V1l, 3, 6};
    g1.s[3] = {nullptr, nullptr, nullptr, nullptr, Qmh, Qml, 2, 0};
    gemm_k<64, 64, 1, 1><<<dim3(24, 32), blk, 0, stream>>>(nullptr, Qsh, Qsl, WB1h, WB1l, g1);

    ln_stats_kernel<<<512, blk, 0, stream>>>(R0, MUpa, RSpa, 2048);

    // G2: CAQ1 = LN(P_A) @ ca1_Wq * sc
    GemmCfg g2{};
    g2.muA = MUpa; g2.rsA = RSpa;
    g2.s[0] = {nullptr, CM, CB, nullptr, Qch, Qcl, 2, 0};
    gemm_k<64, 64, 0, 0><<<dim3(6, 32), blk, 0, stream>>>(R0, nullptr, nullptr, W2h, W2l, g2);

    // CA1 attention (64 keys, final)
    attn_k<192, 192, 4, 0, 1><<<dim3(1, 2, 32), blk, 0, stream>>>(
        Qch, Qcl, K1h, K1l, V1h, V1l, nullptr, Xh, Xl, nullptr, nullptr, 6, 64, 1, 2);

    // G3: P_B = X @ ca1_Wp + bp
    GemmCfg g3{};
    g3.s[0] = {ca1_bp, nullptr, nullptr, R1, nullptr, nullptr, 0, 0};
    gemm_k<64, 64, 1, 0><<<dim3(6, 32), blk, 0, stream>>>(nullptr, Xh, Xl, W3h, W3l, g3);

    ln_stats_kernel<<<512, blk, 0, stream>>>(R1, MUpb, RSpb, 2048);

    // G4: CAQ2 = LN(P_B) @ ca2_Wq * sc
    GemmCfg g4{};
    g4.muA = MUpb; g4.rsA = RSpb;
    g4.s[0] = {nullptr, CM + 1152, CB + 1152, nullptr, Qch, Qcl, 2, 0};
    gemm_k<64, 64, 0, 0><<<dim3(6, 32), blk, 0, stream>>>(R1, nullptr, nullptr, W4h, W4l, g4);

    // CA2 attention (1024 keys, 8 chunks) + combine
    attn_k<192, 192, 4, 0, 0><<<dim3(8, 2, 32), blk, 0, stream>>>(
        Qch, Qcl, K2h, K2l, V2h, V2l, nullptr, nullptr, nullptr, OP, MLb, 10, 128, 8, 2);
    comb_k<192><<<1024, blk, 0, stream>>>(OP, MLb, Xh, Xl, 8, 2);

    // G67: T = tanh(X @ W67 + b67)
    GemmCfg g67{};
    g67.s[0] = {CB + 2304, nullptr, nullptr, R0, nullptr, nullptr, 1, 0};
    gemm_k<64, 64, 1, 0><<<dim3(6, 32), blk, 0, stream>>>(nullptr, Xh, Xl, W67h, W67l, g67);

    pt_kernel<<<512, blk, 0, stream>>>(R0, vp_w, vp_b, PTb, 2048);

    // G5b: main K/V projection (aliased onto K2/V2 region; CA2 done reading it)
    GemmCfg g5b{};
    g5b.s[0] = {nullptr, nullptr, nullptr, nullptr, Kmh, Kml, 2, 0};
    g5b.s[1] = {nullptr, nullptr, nullptr, nullptr, Vmh, Vml, 3, 10};
    gemm_big<1><<<dim3(6, 256), dim3(512), 0, stream>>>(KVsh, KVsl,
        WB5h + 768 * 384, WB5l + 768 * 384, g5b);

    // main attention (gauss, 8 chunks) + combine
    attn_k<48, 64, 4, 1, 0><<<dim3(8, 8, 32), blk, 0, stream>>>(
        Qmh, Qml, Kmh, Kml, Vmh, Vml, PTb, nullptr, nullptr, OP, MLb, 10, 128, 8, 8);
    comb_k<48><<<4096, blk, 0, stream>>>(OP, MLb, Xh, Xl, 8, 8);

    // G10: out = X @ Wproj + bproj
    GemmCfg g10{};
    g10.s[0] = {bproj, nullptr, nullptr, out, nullptr, nullptr, 0, 0};
    gemm_k<64, 64, 1, 0><<<dim3(6, 32), blk, 0, stream>>>(nullptr, Xh, Xl, W10h, W10l, g10);
}